// Round 4
// baseline (377.840 us; speedup 1.0000x reference)
//
#include <hip/hip_runtime.h>
#include <hip/hip_bf16.h>
#include <math.h>

typedef __attribute__((ext_vector_type(4))) float f32x4;
typedef __attribute__((ext_vector_type(8))) short bf16x8;

#define N_ROWS 8192
#define D 256
#define MSHIFT 16.0f

__device__ __forceinline__ unsigned short f2bf(float f) {
    unsigned int u = __float_as_uint(f);
    unsigned int r = u + 0x7FFFu + ((u >> 16) & 1u);
    return (unsigned short)(r >> 16);
}

__device__ __forceinline__ float breduce_sum256(float v, float* sb) {
#pragma unroll
    for (int off = 32; off; off >>= 1) v += __shfl_down(v, off);
    int wid = threadIdx.x >> 6;
    __syncthreads();
    if ((threadIdx.x & 63) == 0) sb[wid] = v;
    __syncthreads();
    return sb[0] + sb[1] + sb[2] + sb[3];
}

__device__ __forceinline__ void dma16(const void* g, void* l) {
    __builtin_amdgcn_global_load_lds(
        (const __attribute__((address_space(1))) unsigned int*)g,
        (__attribute__((address_space(3))) unsigned int*)l, 16, 0, 0);
}

// expand 8 adjacency bits (starting at bit sh of w32) to bf16 0/1
__device__ __forceinline__ bf16x8 bits2bf(unsigned int w32, int sh) {
    unsigned int m = w32 >> sh;
    bf16x8 r;
#pragma unroll
    for (int j = 0; j < 8; ++j)
        r[j] = (m & (1u << j)) ? (short)0x3F80 : (short)0;
    return r;
}

// K2: M2[k][j] = sum_m W_gcn[k][m] * W_att[m+1][j]
__global__ void k_M2(const float* __restrict__ Wg, const float* __restrict__ Wa,
                     float* __restrict__ M2) {
    int k = blockIdx.x, t = threadIdx.x;
    float acc = 0.f;
#pragma unroll 8
    for (int m = 0; m < 255; ++m)
        acc += Wg[k * 255 + m] * Wa[(m + 1) * 256 + t];
    M2[k * 256 + t] = acc;
}

// K3: fused logmap0 + h-GEMV + cvec/wexp + direct GT write (GT[c][j] = bf16(wexp[j]*h[j][c]))
__global__ void k_h2(const float* __restrict__ x, const float* __restrict__ M2,
                     const float* __restrict__ aatt,
                     float* __restrict__ wexp, unsigned short* __restrict__ GT) {
    __shared__ float sb[4];
    __shared__ float Ls[8][256];
    int i0 = blockIdx.x * 8, t = threadIdx.x;
#pragma unroll
    for (int r = 0; r < 8; ++r) {
        float xv = x[(size_t)(i0 + r) * D + t];
        float yv = (t >= 1) ? xv : 0.f;
        float ss = breduce_sum256(yv * yv, sb);
        float ynorm = fmaxf(sqrtf(ss), 1e-15f);
        float x0 = x[(size_t)(i0 + r) * D];
        float th = fmaxf(x0, 1.f + 1e-7f);
        float al = acoshf(th);
        Ls[r][t] = (t >= 1) ? (al * yv / ynorm) : 0.f;
    }
    __syncthreads();
    float acc[8] = {0.f, 0.f, 0.f, 0.f, 0.f, 0.f, 0.f, 0.f};
#pragma unroll 4
    for (int k = 0; k < 255; ++k) {
        float m2 = M2[k * 256 + t];
#pragma unroll
        for (int r = 0; r < 8; ++r) acc[r] += Ls[r][k + 1] * m2;
    }
    float a2 = aatt[256 + t];
    float wr[8];
#pragma unroll
    for (int r = 0; r < 8; ++r) {
        float s = breduce_sum256(acc[r] * a2, sb);
        wr[r] = expf(s - MSHIFT);
        if (t == r) wexp[i0 + r] = wr[r];
    }
    bf16x8 g;
#pragma unroll
    for (int r = 0; r < 8; ++r) g[r] = (short)f2bf(acc[r] * wr[r]);
    *(bf16x8*)(GT + (size_t)t * N_ROWS + i0) = g;
}

// K4: stream adj once -> 1-bit mask + exact fp32 rowsum[i] = sum_k adj[i][k]*wexp[k]
__global__ void k_pack(const int* __restrict__ adj, const float* __restrict__ wexp,
                       unsigned int* __restrict__ pack, float* __restrict__ rowsum) {
    __shared__ float sb[4];
    int row = blockIdx.x, t = threadIdx.x;
    const int4* ap = (const int4*)(adj + (size_t)row * N_ROWS) + t * 8;
    const float4* wp = (const float4*)(wexp) + t * 8;
    unsigned int word = 0;
    float rsum = 0.f;
#pragma unroll
    for (int q = 0; q < 8; ++q) {
        int4 a = ap[q];
        float4 wv = wp[q];
        if (a.x) { word |= 1u << (q * 4 + 0); rsum += wv.x; }
        if (a.y) { word |= 1u << (q * 4 + 1); rsum += wv.y; }
        if (a.z) { word |= 1u << (q * 4 + 2); rsum += wv.z; }
        if (a.w) { word |= 1u << (q * 4 + 3); rsum += wv.w; }
    }
    pack[row * 256 + t] = word;
    float s = breduce_sum256(rsum, sb);
    if (t == 0) rowsum[row] = s;
}

// K6: masked GEMM from bit-mask A (VALU expand) + DMA-staged B (GT, L2-hot).
// BM=64, BN=256, BK=64. 256 thr (4 waves). grid = 128 row-blocks * nkb (split-K).
__global__ void __launch_bounds__(256, 4)
k_attbits(const unsigned int* __restrict__ pack, const unsigned short* __restrict__ GT,
          float* __restrict__ part, int krange) {
    __shared__ __align__(16) unsigned short Bs[256 * 64]; // 32 KB, swizzled rows (128 B)
    const int tid = threadIdx.x;
    const int rb = blockIdx.x & 127;
    const int kb = blockIdx.x >> 7;
    const int i0 = rb * 64;
    const int kbeg = kb * krange;
    const int w = tid >> 6, l = tid & 63;
    const int lr = l & 15, lk = (l >> 4) * 8;

    // B staging: pre-swizzled global source, linear LDS dest (rule #21)
    const unsigned short* srcB[8];
    char* ldsB0 = (char*)Bs + w * 8192;
#pragma unroll
    for (int j = 0; j < 8; ++j) {
        int col = (w * 8 + j) * 8 + (l >> 3);
        srcB[j] = GT + (size_t)col * N_ROWS + kbeg + (((l & 7) ^ (col & 7)) << 3);
    }
    // A bit-row word offsets (rows m*16+lr)
    int aoff[4];
#pragma unroll
    for (int m = 0; m < 4; ++m) aoff[m] = (i0 + m * 16 + lr) * (N_ROWS / 32);

    f32x4 zero4 = {0.f, 0.f, 0.f, 0.f};
    f32x4 acc[4][4];
#pragma unroll
    for (int m = 0; m < 4; ++m)
#pragma unroll
        for (int n = 0; n < 4; ++n) acc[m][n] = zero4;

    const int nsteps = krange / 64;
    for (int kt = 0; kt < nsteps; ++kt) {
        const int k0 = kbeg + kt * 64;
        if (kt) __syncthreads();
#pragma unroll
        for (int j = 0; j < 8; ++j)
            dma16(srcB[j] + kt * 64, ldsB0 + j * 1024);
        // A bits: 4 x 8B loads (L1/L2-hot), issued under the DMA
        uint2 pk[4];
#pragma unroll
        for (int m = 0; m < 4; ++m)
            pk[m] = *(const uint2*)(pack + aoff[m] + (k0 >> 5));
        __syncthreads();   // drains vmcnt(0): B staged
#pragma unroll
        for (int ks = 0; ks < 2; ++ks) {
            const int kbB = (ks * 32 + lk) * 2;
            const int sw = (lr & 7) << 4;
            bf16x8 bfr[4];
#pragma unroll
            for (int n = 0; n < 4; ++n) {
                const char* p = (const char*)Bs + (w * 64 + n * 16 + lr) * 128;
                bfr[n] = *(const bf16x8*)(p + (kbB ^ sw));
            }
#pragma unroll
            for (int m = 0; m < 4; ++m) {
                unsigned int wd = ks ? pk[m].y : pk[m].x;
                bf16x8 af = bits2bf(wd, lk);
#pragma unroll
                for (int n = 0; n < 4; ++n)
                    acc[m][n] = __builtin_amdgcn_mfma_f32_16x16x32_bf16(af, bfr[n], acc[m][n], 0, 0, 0);
            }
        }
    }

    // C write (layout: col=lane&15, row=(lane>>4)*4+reg)
    float* pbase = part + (size_t)kb * N_ROWS * D;
#pragma unroll
    for (int m = 0; m < 4; ++m)
#pragma unroll
        for (int n = 0; n < 4; ++n) {
            int orow = i0 + m * 16 + ((l >> 4) << 2);
            int ocol = (w << 6) + (n << 4) + lr;
            float* op = pbase + (size_t)orow * D + ocol;
#pragma unroll
            for (int v = 0; v < 4; ++v) op[(size_t)v * D] = acc[m][n][v];
        }
}

// K7: split-K reduce + epilogue (divide, elu, proj, logmap0, sigmoid, expmap0)
__global__ void k_final3(const float* __restrict__ part, const float* __restrict__ rowsum,
                         float* __restrict__ out, int nkb) {
    __shared__ float sb[4];
    int row = blockIdx.x, t = threadIdx.x;
    float raw = 0.f;
    for (int kb = 0; kb < nkb; ++kb)
        raw += part[((size_t)kb * N_ROWS + row) * D + t];
    float rs = rowsum[row];
    float hp = raw / rs;
    float ey = 0.f;
    if (t >= 1) ey = (hp > 0.f) ? hp : expm1f(hp);
    float ss = breduce_sum256(ey * ey, sb);
    float x0 = sqrtf(1.f + ss);
    float th = fmaxf(x0, 1.f + 1e-7f);
    float al = acoshf(th);
    float yn = fmaxf(sqrtf(ss), 1e-15f);
    float u = (t >= 1) ? (al * ey / yn) : 0.f;
    float s = 1.f / (1.f + expf(-u));
    float s2 = (t >= 1) ? s * s : 0.f;
    float ssn = breduce_sum256(s2, sb);
    float xn = fmaxf(sqrtf(ssn), 1e-15f);
    float sh = sinhf(xn);
    float yf = (t >= 1) ? (sh * s / xn) : 0.f;
    float sy = breduce_sum256(yf * yf, sb);
    float res = (t == 0) ? sqrtf(1.f + sy) : yf;
    out[(size_t)row * D + t] = res;
}

extern "C" void kernel_launch(void* const* d_in, const int* in_sizes, int n_in,
                              void* d_out, int out_size, void* d_ws, size_t ws_size,
                              hipStream_t stream) {
    const float* x    = (const float*)d_in[0];
    const int*   adj  = (const int*)d_in[1];
    const float* Wg   = (const float*)d_in[3];
    const float* Wa   = (const float*)d_in[4];
    const float* aatt = (const float*)d_in[5];
    float* out = (float*)d_out;

    char* wsb = (char*)d_ws;
    unsigned int*   pack   = (unsigned int*)(wsb);                // 8 MB
    float*          M2     = (float*)(wsb + 0x0800000);           // 256 KB
    unsigned short* GT     = (unsigned short*)(wsb + 0x0840000);  // 4 MB
    float*          wexp   = (float*)(wsb + 0x0C40000);           // 32 KB
    float*          rowsum = (float*)(wsb + 0x0C48000);           // 32 KB
    float*          part   = (float*)(wsb + 0x0C50000);           // nkb * 8 MB

    // split-K factor bounded by available workspace (evidence: ws ~1 GB)
    size_t base = 0x0C50000;
    int nkb = 2;
    if (ws_size >= base + 8ull * 0x800000) nkb = 8;
    else if (ws_size >= base + 4ull * 0x800000) nkb = 4;
    int krange = N_ROWS / nkb;

    k_M2<<<255, 256, 0, stream>>>(Wg, Wa, M2);
    k_h2<<<N_ROWS / 8, 256, 0, stream>>>(x, M2, aatt, wexp, GT);
    k_pack<<<N_ROWS, 256, 0, stream>>>(adj, wexp, pack, rowsum);
    k_attbits<<<128 * nkb, 256, 0, stream>>>(pack, GT, part, krange);
    k_final3<<<N_ROWS, 256, 0, stream>>>(part, rowsum, out, nkb);
}

// Round 5
// 209.197 us; speedup vs baseline: 1.8061x; 1.8061x over previous
//
#include <hip/hip_runtime.h>
#include <hip/hip_bf16.h>
#include <math.h>

typedef __attribute__((ext_vector_type(4))) float f32x4;
typedef __attribute__((ext_vector_type(8))) short bf16x8;

#define N_ROWS 8192
#define D 256
#define MSHIFT 16.0f
#define NKB 4
#define KRANGE (N_ROWS / NKB)     // 2048
#define NSTEP (KRANGE / 32)       // 64

__device__ __forceinline__ unsigned short f2bf(float f) {
    unsigned int u = __float_as_uint(f);
    unsigned int r = u + 0x7FFFu + ((u >> 16) & 1u);
    return (unsigned short)(r >> 16);
}

__device__ __forceinline__ float breduce_sum256(float v, float* sb) {
#pragma unroll
    for (int off = 32; off; off >>= 1) v += __shfl_down(v, off);
    int wid = threadIdx.x >> 6;
    __syncthreads();
    if ((threadIdx.x & 63) == 0) sb[wid] = v;
    __syncthreads();
    return sb[0] + sb[1] + sb[2] + sb[3];
}

__device__ __forceinline__ void dma16(const void* g, void* l) {
    __builtin_amdgcn_global_load_lds(
        (const __attribute__((address_space(1))) unsigned int*)g,
        (__attribute__((address_space(3))) unsigned int*)l, 16, 0, 0);
}

__device__ __forceinline__ bf16x8 adj2bf(int4 a, int4 b) {
    bf16x8 r;
    r[0] = a.x ? (short)0x3F80 : (short)0;
    r[1] = a.y ? (short)0x3F80 : (short)0;
    r[2] = a.z ? (short)0x3F80 : (short)0;
    r[3] = a.w ? (short)0x3F80 : (short)0;
    r[4] = b.x ? (short)0x3F80 : (short)0;
    r[5] = b.y ? (short)0x3F80 : (short)0;
    r[6] = b.z ? (short)0x3F80 : (short)0;
    r[7] = b.w ? (short)0x3F80 : (short)0;
    return r;
}

// K2: M2[k][j] = sum_m W_gcn[k][m] * W_att[m+1][j]
__global__ void k_M2(const float* __restrict__ Wg, const float* __restrict__ Wa,
                     float* __restrict__ M2) {
    int k = blockIdx.x, t = threadIdx.x;
    float acc = 0.f;
#pragma unroll 8
    for (int m = 0; m < 255; ++m)
        acc += Wg[k * 255 + m] * Wa[(m + 1) * 256 + t];
    M2[k * 256 + t] = acc;
}

// K3: fused logmap0 + h-GEMV + attention-weight exp + direct GT write
__global__ void k_h2(const float* __restrict__ x, const float* __restrict__ M2,
                     const float* __restrict__ aatt,
                     unsigned short* __restrict__ wbf, unsigned short* __restrict__ GT) {
    __shared__ float sb[4];
    __shared__ float Ls[8][256];
    int i0 = blockIdx.x * 8, t = threadIdx.x;
#pragma unroll
    for (int r = 0; r < 8; ++r) {
        float xv = x[(size_t)(i0 + r) * D + t];
        float yv = (t >= 1) ? xv : 0.f;
        float ss = breduce_sum256(yv * yv, sb);
        float ynorm = fmaxf(sqrtf(ss), 1e-15f);
        float x0 = x[(size_t)(i0 + r) * D];
        float th = fmaxf(x0, 1.f + 1e-7f);
        float al = acoshf(th);
        Ls[r][t] = (t >= 1) ? (al * yv / ynorm) : 0.f;
    }
    __syncthreads();
    float acc[8] = {0.f, 0.f, 0.f, 0.f, 0.f, 0.f, 0.f, 0.f};
#pragma unroll 4
    for (int k = 0; k < 255; ++k) {
        float m2 = M2[k * 256 + t];
#pragma unroll
        for (int r = 0; r < 8; ++r) acc[r] += Ls[r][k + 1] * m2;
    }
    float a2 = aatt[256 + t];
    float wr[8];
#pragma unroll
    for (int r = 0; r < 8; ++r) {
        float s = breduce_sum256(acc[r] * a2, sb);
        wr[r] = expf(s - MSHIFT);
        if (t == r) wbf[i0 + r] = f2bf(wr[r]);
    }
    bf16x8 g;
#pragma unroll
    for (int r = 0; r < 8; ++r) g[r] = (short)f2bf(acc[r] * wr[r]);
    *(bf16x8*)(GT + (size_t)t * N_ROWS + i0) = g;
}

// K6: masked GEMM reading adj ONCE, inside the loop. BM=64, BN=256, BK=32.
// Double-buffered LDS via global_load_lds, counted vmcnt(6), raw s_barrier.
// A and B tiles XOR-swizzled (pre-swizzled global source + swizzled ds_read).
// Rowsum folded in as a wexp bf16 B-column.
__global__ void __launch_bounds__(256, 2)
k_attadj(const int* __restrict__ adj, const unsigned short* __restrict__ GT,
         const unsigned short* __restrict__ wbf, float* __restrict__ part,
         float* __restrict__ rspart) {
    __shared__ __align__(16) char bufA[2][8192];   // 64 rows x 32 ints (128 B rows)
    __shared__ __align__(16) char bufB[2][16384];  // 256 cols x 32 bf16 (64 B rows)
    __shared__ __align__(16) char wlds[4096];      // KRANGE bf16 weights
    const int tid = threadIdx.x;
    const int rb = blockIdx.x & 127;
    const int kb = blockIdx.x >> 7;
    const int i0 = rb * 64;
    const int kbeg = kb * KRANGE;
    const int w = tid >> 6, l = tid & 63;
    const int lr = l & 15, lq = l >> 4;

    // ---- DMA sources (pre-swizzled global addresses; LDS dests linear)
    // A: insts a = w*2+{0,1}; row = a*8 + (l>>3); granule(16B=4 ints) = (l&7) ^ (row&7)
    const int a0 = w * 2, a1 = a0 + 1;
    const int ra0 = a0 * 8 + (l >> 3), ra1 = a1 * 8 + (l >> 3);
    const int pgA = (l & 7) ^ ((l >> 3) & 7);
    const int* srcA0 = adj + (size_t)(i0 + ra0) * N_ROWS + kbeg + pgA * 4;
    const int* srcA1 = adj + (size_t)(i0 + ra1) * N_ROWS + kbeg + pgA * 4;
    // B: insts b = w*4+j; col = b*16 + (l>>2); granule(16B=8 bf16) = (l&3) ^ swz(col)
    const int bswz = ((l >> 2) & 3) ^ ((l >> 4) & 3);
    const unsigned short* srcB0 = GT + (size_t)((w * 4 + 0) * 16 + (l >> 2)) * N_ROWS + kbeg + ((l & 3) ^ bswz) * 8;
    const unsigned short* srcB1 = GT + (size_t)((w * 4 + 1) * 16 + (l >> 2)) * N_ROWS + kbeg + ((l & 3) ^ bswz) * 8;
    const unsigned short* srcB2 = GT + (size_t)((w * 4 + 2) * 16 + (l >> 2)) * N_ROWS + kbeg + ((l & 3) ^ bswz) * 8;
    const unsigned short* srcB3 = GT + (size_t)((w * 4 + 3) * 16 + (l >> 2)) * N_ROWS + kbeg + ((l & 3) ^ bswz) * 8;

#define STAGE(t) do {                                              \
        const int koff_ = (t) * 32;                                \
        char* bA_ = bufA[(t) & 1]; char* bB_ = bufB[(t) & 1];      \
        dma16(srcA0 + koff_, bA_ + a0 * 1024);                     \
        dma16(srcA1 + koff_, bA_ + a1 * 1024);                     \
        dma16(srcB0 + koff_, bB_ + (w * 4 + 0) * 1024);            \
        dma16(srcB1 + koff_, bB_ + (w * 4 + 1) * 1024);            \
        dma16(srcB2 + koff_, bB_ + (w * 4 + 2) * 1024);            \
        dma16(srcB3 + koff_, bB_ + (w * 4 + 3) * 1024);            \
    } while (0)

    f32x4 zero4 = {0.f, 0.f, 0.f, 0.f};
    f32x4 acc[4][4], acc_rs[4];
#pragma unroll
    for (int m = 0; m < 4; ++m) {
        acc_rs[m] = zero4;
#pragma unroll
        for (int n = 0; n < 4; ++n) acc[m][n] = zero4;
    }

    // prologue: stage step 0 + weight tile (7 DMAs outstanding)
    STAGE(0);
    dma16(wbf + kbeg + w * 512 + l * 8, wlds + w * 1024);

    // read-side swizzled offsets (lane-constant)
    const int gA0 = lr * 128 + (((2 * lq) ^ (lr & 7)) << 4);
    const int gA1 = lr * 128 + (((2 * lq + 1) ^ (lr & 7)) << 4);
    const int gB = lr * 64 + ((lq ^ (lr & 3) ^ ((lr >> 2) & 3)) << 4);

    for (int t = 0; t < NSTEP; ++t) {
        if (t + 1 < NSTEP) {
            STAGE(t + 1);
            asm volatile("s_waitcnt vmcnt(6)" ::: "memory");
        } else {
            asm volatile("s_waitcnt vmcnt(0)" ::: "memory");
        }
        __builtin_amdgcn_sched_barrier(0);
        __builtin_amdgcn_s_barrier();
        const char* bA = bufA[t & 1];
        const char* bB = bufB[t & 1];

        bf16x8 wf = {0, 0, 0, 0, 0, 0, 0, 0};
        if (lr == 0) wf = *(const bf16x8*)(wlds + t * 64 + lq * 16);

        bf16x8 af[4];
#pragma unroll
        for (int m = 0; m < 4; ++m) {
            int4 u = *(const int4*)(bA + m * 2048 + gA0);
            int4 v = *(const int4*)(bA + m * 2048 + gA1);
            af[m] = adj2bf(u, v);
        }
#pragma unroll
        for (int n = 0; n < 4; ++n) {
            bf16x8 bf = *(const bf16x8*)(bB + w * 4096 + n * 1024 + gB);
#pragma unroll
            for (int m = 0; m < 4; ++m)
                acc[m][n] = __builtin_amdgcn_mfma_f32_16x16x32_bf16(af[m], bf, acc[m][n], 0, 0, 0);
        }
#pragma unroll
        for (int m = 0; m < 4; ++m)
            acc_rs[m] = __builtin_amdgcn_mfma_f32_16x16x32_bf16(af[m], wf, acc_rs[m], 0, 0, 0);
        __builtin_amdgcn_sched_barrier(0);
        __builtin_amdgcn_s_barrier();
    }
#undef STAGE

    // rowsum (col 0 of acc_rs; waves identical, wave 0 writes)
    if (w == 0 && lr == 0) {
#pragma unroll
        for (int m = 0; m < 4; ++m)
#pragma unroll
            for (int v = 0; v < 4; ++v)
                rspart[(size_t)kb * N_ROWS + i0 + m * 16 + lq * 4 + v] = acc_rs[m][v];
    }

    // C write (layout: col=lane&15, row=(lane>>4)*4+reg)
    float* pbase = part + (size_t)kb * N_ROWS * D;
#pragma unroll
    for (int m = 0; m < 4; ++m)
#pragma unroll
        for (int n = 0; n < 4; ++n) {
            int orow = i0 + m * 16 + lq * 4;
            int ocol = (w << 6) + (n << 4) + lr;
            float* op = pbase + (size_t)orow * D + ocol;
#pragma unroll
            for (int v = 0; v < 4; ++v) op[(size_t)v * D] = acc[m][n][v];
        }
}

// K7: split-K reduce + epilogue (divide, elu, proj, logmap0, sigmoid, expmap0)
__global__ void k_final3(const float* __restrict__ part, const float* __restrict__ rspart,
                         float* __restrict__ out) {
    __shared__ float sb[4];
    int row = blockIdx.x, t = threadIdx.x;
    float raw = 0.f, rs = 0.f;
#pragma unroll
    for (int kbi = 0; kbi < NKB; ++kbi) {
        raw += part[((size_t)kbi * N_ROWS + row) * D + t];
        rs += rspart[(size_t)kbi * N_ROWS + row];
    }
    float hp = raw / rs;
    float ey = 0.f;
    if (t >= 1) ey = (hp > 0.f) ? hp : expm1f(hp);
    float ss = breduce_sum256(ey * ey, sb);
    float x0 = sqrtf(1.f + ss);
    float th = fmaxf(x0, 1.f + 1e-7f);
    float al = acoshf(th);
    float yn = fmaxf(sqrtf(ss), 1e-15f);
    float u = (t >= 1) ? (al * ey / yn) : 0.f;
    float s = 1.f / (1.f + expf(-u));
    float s2 = (t >= 1) ? s * s : 0.f;
    float ssn = breduce_sum256(s2, sb);
    float xn = fmaxf(sqrtf(ssn), 1e-15f);
    float sh = sinhf(xn);
    float yf = (t >= 1) ? (sh * s / xn) : 0.f;
    float sy = breduce_sum256(yf * yf, sb);
    float res = (t == 0) ? sqrtf(1.f + sy) : yf;
    out[(size_t)row * D + t] = res;
}

extern "C" void kernel_launch(void* const* d_in, const int* in_sizes, int n_in,
                              void* d_out, int out_size, void* d_ws, size_t ws_size,
                              hipStream_t stream) {
    const float* x    = (const float*)d_in[0];
    const int*   adj  = (const int*)d_in[1];
    const float* Wg   = (const float*)d_in[3];
    const float* Wa   = (const float*)d_in[4];
    const float* aatt = (const float*)d_in[5];
    float* out = (float*)d_out;

    char* wsb = (char*)d_ws;
    float*          M2     = (float*)(wsb);                      // 256 KB
    unsigned short* GT     = (unsigned short*)(wsb + 0x0040000); // 4 MB
    unsigned short* wbf    = (unsigned short*)(wsb + 0x0440000); // 16 KB
    float*          rspart = (float*)(wsb + 0x0448000);          // 128 KB
    float*          part   = (float*)(wsb + 0x0480000);          // 32 MB

    k_M2<<<255, 256, 0, stream>>>(Wg, Wa, M2);
    k_h2<<<N_ROWS / 8, 256, 0, stream>>>(x, M2, aatt, wbf, GT);
    k_attadj<<<128 * NKB, 256, 0, stream>>>(adj, GT, wbf, part, rspart);
    k_final3<<<N_ROWS, 256, 0, stream>>>(part, rspart, out);
}